// Round 6
// baseline (473.355 us; speedup 1.0000x reference)
//
#include <hip/hip_runtime.h>
#include <hip/hip_bf16.h>

#define NROIS 333
#define BATCH 512
#define NREG 300
#define NCLS 180
#define EPSV 1e-5f
#define SLOPEV 0.3f

typedef __attribute__((ext_vector_type(8))) short bf16x8;
typedef __attribute__((ext_vector_type(4))) float f32x4;

static __device__ __forceinline__ bf16x8 pack8(const float v[8]) {
  union { bf16x8 o; __hip_bfloat16 h[8]; } u;
  #pragma unroll
  for (int e = 0; e < 8; e++) u.h[e] = __float2bfloat16(v[e]);
  return u.o;
}

// ---------------- metadata: {in_off, size, out_off, reduced} via binary search ----------------
__global__ void meta_kernel(const int* __restrict__ idx, const int* __restrict__ src,
                            int* __restrict__ meta, int max_in, int max_out,
                            int total, int concat_dim) {
  int r = blockIdx.x * blockDim.x + threadIdx.x;
  if (r >= NROIS) return;
  const int* row = idx + (long)r * max_in;
  int in_off = row[0];
  int lo = 0, hi = max_in;
  while (lo < hi) { int mid = (lo + hi) >> 1; if (row[mid] < total) lo = mid + 1; else hi = mid; }
  int size = lo;
  int t1 = r * max_out;
  lo = 0; hi = concat_dim;
  while (lo < hi) { int mid = (lo + hi) >> 1; if (src[mid] < t1) lo = mid + 1; else hi = mid; }
  int out_off = lo;
  int t2 = t1 + max_out;
  hi = concat_dim;
  while (lo < hi) { int mid = (lo + hi) >> 1; if (src[mid] < t2) lo = mid + 1; else hi = mid; }
  meta[r] = in_off;
  meta[NROIS + r] = size;
  meta[2 * NROIS + r] = out_off;
  meta[3 * NROIS + r] = lo - out_off;
}

__global__ void init_reg_kernel(const float* __restrict__ b_reg, float* __restrict__ reg_out) {
  int i = blockIdx.x * blockDim.x + threadIdx.x;
  if (i < BATCH * NREG) reg_out[i] = b_reg[i % NREG];
}

// ---------------- linear transcode: concat fp32 -> bf16 (padded rows), W_reg fp32 -> bf16 ----------------
__global__ __launch_bounds__(256) void transcode_kernel(
    const float* __restrict__ concat, const float* __restrict__ W_reg,
    __hip_bfloat16* __restrict__ cbf, __hip_bfloat16* __restrict__ wbf,
    int cd, int cdp) {
  int row = blockIdx.x;
  const float* src;
  __hip_bfloat16* dst;
  if (row < BATCH) { src = concat + (long)row * cd; dst = cbf + (long)row * cdp; }
  else             { src = W_reg + (long)(row - BATCH) * cd; dst = wbf + (long)(row - BATCH) * cdp; }
  for (int k = threadIdx.x * 8; k < cdp; k += 256 * 8) {
    if (k + 8 <= cd) {
      float4 a = *(const float4*)(src + k), b = *(const float4*)(src + k + 4);
      float v[8] = {a.x, a.y, a.z, a.w, b.x, b.y, b.z, b.w};
      *(bf16x8*)(dst + k) = pack8(v);
    } else {
      for (int e = 0; e < 8 && k + e < cdp; e++)
        dst[k + e] = __float2bfloat16((k + e < cd) ? src[k + e] : 0.f);
    }
  }
}

// ---------------- encoder: K=32 dbuf-pipelined MFMA + BN + leaky ----------------
// M=128/block. LDS rows = 32 bf16 in 4 chunks, padded to 5 chunks (80 B) -> ~2-way banks, no swizzle.
__global__ __launch_bounds__(256) void enc_kernel(
    const float* __restrict__ x,
    const float* __restrict__ W_enc,
    const float* __restrict__ b_enc,
    const float* __restrict__ gamma,
    const float* __restrict__ beta,
    const float* __restrict__ run_mean,
    const float* __restrict__ run_var,
    const int* __restrict__ meta,
    float* __restrict__ concat_out,
    int total, int max_in, int max_out, int concat_dim) {
  int r = blockIdx.x;
  int b0 = blockIdx.y * 128;
  int in_off  = meta[r];
  int size    = meta[NROIS + r];
  int out_off = meta[2 * NROIS + r];
  int red     = meta[3 * NROIS + r];
  int ntiles  = (red + 15) >> 4;          // 1..4, block-uniform

  __shared__ __hip_bfloat16 xs[2][128][40];
  __shared__ __hip_bfloat16 wsh[2][64][40];

  int t = threadIdx.x;
  int row0 = t >> 2, chk = t & 3;         // staging: rows {row0,row0+64} of x, row0 of W
  const float* xg0 = x + (long)(b0 + row0) * total + in_off;
  long xstride = (long)64 * total;
  int wrow = (row0 < red) ? row0 : (red - 1);   // clamp: garbage cols masked in epilogue
  const float* wg0 = W_enc + ((long)r * max_out + wrow) * max_in;

  int w = t >> 6, l = t & 63, lq = l >> 4, lm = l & 15;

  f32x4 acc[2][4];
  #pragma unroll
  for (int i = 0; i < 2; i++)
    #pragma unroll
    for (int nb = 0; nb < 4; nb++) acc[i][nb] = (f32x4){0.f, 0.f, 0.f, 0.f};

  int nsteps = (size + 31) >> 5;
  float xr[2][8], wr[8];

  auto load_regs = [&](int kb) {
    int k0 = kb + chk * 8;
    if (k0 + 8 <= size) {
      #pragma unroll
      for (int s = 0; s < 2; s++) {
        const float* p = xg0 + (long)s * xstride + k0;
        float4 a = *(const float4*)p, b = *(const float4*)(p + 4);
        xr[s][0]=a.x; xr[s][1]=a.y; xr[s][2]=a.z; xr[s][3]=a.w;
        xr[s][4]=b.x; xr[s][5]=b.y; xr[s][6]=b.z; xr[s][7]=b.w;
      }
      const float* p = wg0 + k0;
      float4 a = *(const float4*)p, b = *(const float4*)(p + 4);
      wr[0]=a.x; wr[1]=a.y; wr[2]=a.z; wr[3]=a.w;
      wr[4]=b.x; wr[5]=b.y; wr[6]=b.z; wr[7]=b.w;
    } else {
      #pragma unroll
      for (int s = 0; s < 2; s++)
        #pragma unroll
        for (int e = 0; e < 8; e++)
          xr[s][e] = (k0 + e < size) ? xg0[(long)s * xstride + k0 + e] : 0.f;
      #pragma unroll
      for (int e = 0; e < 8; e++)
        wr[e] = (k0 + e < size) ? wg0[k0 + e] : 0.f;
    }
  };
  auto write_lds = [&](int buf) {
    #pragma unroll
    for (int s = 0; s < 2; s++)
      *(bf16x8*)&xs[buf][row0 + 64 * s][chk * 8] = pack8(xr[s]);
    *(bf16x8*)&wsh[buf][row0][chk * 8] = pack8(wr);
  };

  load_regs(0);
  write_lds(0);
  __syncthreads();

  for (int s = 0; s < nsteps; s++) {
    int buf = s & 1;
    bool more = (s + 1 < nsteps);
    if (more) load_regs((s + 1) * 32);
    bf16x8 af[2];
    #pragma unroll
    for (int i = 0; i < 2; i++)
      af[i] = *(const bf16x8*)&xs[buf][32 * w + 16 * i + lm][lq * 8];
    for (int nb = 0; nb < ntiles; nb++) {     // block-uniform trip count
      bf16x8 bfr = *(const bf16x8*)&wsh[buf][16 * nb + lm][lq * 8];
      #pragma unroll
      for (int i = 0; i < 2; i++)
        acc[i][nb] = __builtin_amdgcn_mfma_f32_16x16x32_bf16(af[i], bfr, acc[i][nb], 0, 0, 0);
    }
    if (more) write_lds(buf ^ 1);
    __syncthreads();
  }

  long base = (long)r * max_out;
  for (int nb = 0; nb < ntiles; nb++) {
    int oc = nb * 16 + lm;                    // C/D col = lane&15
    if (oc < red) {
      float sc  = gamma[base + oc] * rsqrtf(run_var[base + oc] + EPSV);
      float off = beta[base + oc] + sc * (b_enc[base + oc] - run_mean[base + oc]);
      #pragma unroll
      for (int i = 0; i < 2; i++) {
        #pragma unroll
        for (int j = 0; j < 4; j++) {         // C/D row = lq*4 + j
          int br = b0 + 32 * w + 16 * i + lq * 4 + j;
          float y = sc * acc[i][nb][j] + off;
          y = (y > 0.f) ? y : SLOPEV * y;
          concat_out[(long)br * concat_dim + out_off + oc] = y;
        }
      }
    }
  }
}

// ---------------- reg GEMM: K=32 dbuf pipelined, bf16 or fp32 source, split-K atomics ----------------
template <bool BF>
__global__ __launch_bounds__(256) void reg_kernel(
    const void* __restrict__ Asrc, const void* __restrict__ Bsrc,
    float* __restrict__ reg_out, int cd, int astride, int span) {
  int j0 = blockIdx.x * 64;
  int b0 = blockIdx.y * 128;
  int kstart = blockIdx.z * span;
  int kend = min(kstart + span, cd);
  if (kstart >= kend) return;               // uniform exit
  int ntiles = min(4, (NREG - j0 + 15) >> 4);

  __shared__ __hip_bfloat16 as_[2][128][40];
  __shared__ __hip_bfloat16 bs_[2][64][40];

  int t = threadIdx.x;
  int row0 = t >> 2, chk = t & 3;
  int jr = j0 + row0;
  int bj = (jr < NREG) ? jr : (NREG - 1);   // clamp: cols >= NREG masked at store
  const __hip_bfloat16* aB = (const __hip_bfloat16*)Asrc + (long)(b0 + row0) * astride + kstart;
  const __hip_bfloat16* bB = (const __hip_bfloat16*)Bsrc + (long)bj * astride + kstart;
  const float* aF = (const float*)Asrc + (long)(b0 + row0) * astride + kstart;
  const float* bF = (const float*)Bsrc + (long)bj * astride + kstart;
  long astr = (long)64 * astride;
  int klen = kend - kstart;

  int w = t >> 6, l = t & 63, lq = l >> 4, lm = l & 15;

  f32x4 acc[2][4];
  #pragma unroll
  for (int i = 0; i < 2; i++)
    #pragma unroll
    for (int nb = 0; nb < 4; nb++) acc[i][nb] = (f32x4){0.f, 0.f, 0.f, 0.f};

  int nsteps = (klen + 31) >> 5;
  bf16x8 arv[2], brv;
  float arf[2][8], brf[8];

  auto load_regs = [&](int kb) {
    int k0 = kb + chk * 8;
    if (k0 + 8 <= klen) {
      if (BF) {
        #pragma unroll
        for (int s = 0; s < 2; s++) arv[s] = *(const bf16x8*)(aB + (long)s * astr + k0);
        brv = *(const bf16x8*)(bB + k0);
      } else {
        #pragma unroll
        for (int s = 0; s < 2; s++) {
          const float* p = aF + (long)s * astr + k0;
          float4 a = *(const float4*)p, b = *(const float4*)(p + 4);
          arf[s][0]=a.x; arf[s][1]=a.y; arf[s][2]=a.z; arf[s][3]=a.w;
          arf[s][4]=b.x; arf[s][5]=b.y; arf[s][6]=b.z; arf[s][7]=b.w;
        }
        const float* p = bF + k0;
        float4 a = *(const float4*)p, b = *(const float4*)(p + 4);
        brf[0]=a.x; brf[1]=a.y; brf[2]=a.z; brf[3]=a.w;
        brf[4]=b.x; brf[5]=b.y; brf[6]=b.z; brf[7]=b.w;
      }
    } else {
      union { bf16x8 v; __hip_bfloat16 h[8]; } ua[2], ub;
      #pragma unroll
      for (int s = 0; s < 2; s++)
        #pragma unroll
        for (int e = 0; e < 8; e++) {
          bool in = (k0 + e < klen);
          if (BF) ua[s].h[e] = in ? aB[(long)s * astr + k0 + e] : __float2bfloat16(0.f);
          else    arf[s][e] = in ? aF[(long)s * astr + k0 + e] : 0.f;
        }
      #pragma unroll
      for (int e = 0; e < 8; e++) {
        bool in = (k0 + e < klen);
        if (BF) ub.h[e] = in ? bB[k0 + e] : __float2bfloat16(0.f);
        else    brf[e] = in ? bF[k0 + e] : 0.f;
      }
      if (BF) { arv[0] = ua[0].v; arv[1] = ua[1].v; brv = ub.v; }
    }
  };
  auto write_lds = [&](int buf) {
    #pragma unroll
    for (int s = 0; s < 2; s++)
      *(bf16x8*)&as_[buf][row0 + 64 * s][chk * 8] = BF ? arv[s] : pack8(arf[s]);
    *(bf16x8*)&bs_[buf][row0][chk * 8] = BF ? brv : pack8(brf);
  };

  load_regs(0);
  write_lds(0);
  __syncthreads();

  for (int s = 0; s < nsteps; s++) {
    int buf = s & 1;
    bool more = (s + 1 < nsteps);
    if (more) load_regs((s + 1) * 32);
    bf16x8 af[2];
    #pragma unroll
    for (int i = 0; i < 2; i++)
      af[i] = *(const bf16x8*)&as_[buf][32 * w + 16 * i + lm][lq * 8];
    for (int nb = 0; nb < ntiles; nb++) {
      bf16x8 bfr = *(const bf16x8*)&bs_[buf][16 * nb + lm][lq * 8];
      #pragma unroll
      for (int i = 0; i < 2; i++)
        acc[i][nb] = __builtin_amdgcn_mfma_f32_16x16x32_bf16(af[i], bfr, acc[i][nb], 0, 0, 0);
    }
    if (more) write_lds(buf ^ 1);
    __syncthreads();
  }

  for (int nb = 0; nb < ntiles; nb++) {
    int j = j0 + nb * 16 + lm;
    if (j < NREG) {
      #pragma unroll
      for (int i = 0; i < 2; i++)
        #pragma unroll
        for (int jj = 0; jj < 4; jj++) {
          int br2 = b0 + 32 * w + 16 * i + lq * 4 + jj;
          atomicAdd(&reg_out[(long)br2 * NREG + j], acc[i][nb][jj]);
        }
    }
  }
}

// ---------------- cls: read reg_out, 180-wide GEMV (float4), softmax ----------------
__global__ __launch_bounds__(192) void cls_kernel(
    const float* __restrict__ reg_out,
    const float* __restrict__ W_cls,
    const float* __restrict__ b_cls,
    float* __restrict__ cls_out) {
  int b = blockIdx.x;
  int t = threadIdx.x;
  __shared__ __align__(16) float rrow[NREG];
  __shared__ float lm[3];
  for (int iB = t; iB < NREG; iB += 192) rrow[iB] = reg_out[(long)b * NREG + iB];
  __syncthreads();
  float s = 0.f;
  if (t < NCLS) {
    s = b_cls[t];
    const float4* wr  = (const float4*)(W_cls + (long)t * NREG);
    const float4* rr4 = (const float4*)rrow;
    #pragma unroll 5
    for (int i = 0; i < NREG / 4; ++i) {
      float4 wv = wr[i], rv = rr4[i];
      s += wv.x * rv.x + wv.y * rv.y + wv.z * rv.z + wv.w * rv.w;
    }
  }
  float v = (t < NCLS) ? s : -3.4e38f;
  #pragma unroll
  for (int o = 32; o > 0; o >>= 1) v = fmaxf(v, __shfl_xor(v, o, 64));
  if ((t & 63) == 0) lm[t >> 6] = v;
  __syncthreads();
  float bmax = fmaxf(fmaxf(lm[0], lm[1]), lm[2]);
  __syncthreads();
  float e = (t < NCLS) ? __expf(s - bmax) : 0.f;
  float ss = e;
  #pragma unroll
  for (int o = 32; o > 0; o >>= 1) ss += __shfl_xor(ss, o, 64);
  if ((t & 63) == 0) lm[t >> 6] = ss;
  __syncthreads();
  float bsum = lm[0] + lm[1] + lm[2];
  if (t < NCLS) cls_out[(long)b * NCLS + t] = e / bsum;
}

extern "C" void kernel_launch(void* const* d_in, const int* in_sizes, int n_in,
                              void* d_out, int out_size, void* d_ws, size_t ws_size,
                              hipStream_t stream) {
  const float* x     = (const float*)d_in[0];
  const float* W_enc = (const float*)d_in[1];
  const float* b_enc = (const float*)d_in[2];
  const float* gam   = (const float*)d_in[3];
  const float* bet   = (const float*)d_in[4];
  const float* rmean = (const float*)d_in[5];
  const float* rvar  = (const float*)d_in[6];
  const float* W_reg = (const float*)d_in[7];
  const float* b_reg = (const float*)d_in[8];
  const float* W_cls = (const float*)d_in[9];
  const float* b_cls = (const float*)d_in[10];
  const int* idx = (const int*)d_in[11];
  const int* src = (const int*)d_in[12];

  int total      = in_sizes[0] / BATCH;
  int max_out    = in_sizes[2] / NROIS;
  int max_in     = in_sizes[11] / NROIS;
  int concat_dim = in_sizes[12];
  int cdp        = (concat_dim + 7) & ~7;   // padded bf16 row stride

  int* meta = (int*)d_ws;
  size_t bf_off = 8192;
  size_t cbf_bytes = (size_t)BATCH * cdp * sizeof(__hip_bfloat16);
  size_t wbf_bytes = (size_t)NREG * cdp * sizeof(__hip_bfloat16);
  int use_bf = (ws_size >= bf_off + cbf_bytes + wbf_bytes) ? 1 : 0;
  __hip_bfloat16* cbf = (__hip_bfloat16*)((char*)d_ws + bf_off);
  __hip_bfloat16* wbf = (__hip_bfloat16*)((char*)d_ws + bf_off + cbf_bytes);

  float* out_concat = (float*)d_out;
  float* out_reg = out_concat + (long)BATCH * concat_dim;
  float* out_cls = out_reg + (long)BATCH * NREG;

  meta_kernel<<<dim3((NROIS + 255) / 256), 256, 0, stream>>>(idx, src, meta, max_in, max_out, total, concat_dim);
  init_reg_kernel<<<dim3((BATCH * NREG + 255) / 256), 256, 0, stream>>>(b_reg, out_reg);
  enc_kernel<<<dim3(NROIS, BATCH / 128), 256, 0, stream>>>(x, W_enc, b_enc, gam, bet, rmean, rvar,
                                                           meta, out_concat, total, max_in, max_out, concat_dim);
  const int SPLIT = 32;
  int span = ((concat_dim + SPLIT * 32 - 1) / (SPLIT * 32)) * 32;
  dim3 rgrid((NREG + 63) / 64, BATCH / 128, SPLIT);
  if (use_bf) {
    transcode_kernel<<<BATCH + NREG, 256, 0, stream>>>(out_concat, W_reg, cbf, wbf, concat_dim, cdp);
    reg_kernel<true><<<rgrid, 256, 0, stream>>>(cbf, wbf, out_reg, concat_dim, cdp, span);
  } else {
    reg_kernel<false><<<rgrid, 256, 0, stream>>>(out_concat, W_reg, out_reg, concat_dim, concat_dim, span);
  }
  cls_kernel<<<BATCH, 192, 0, stream>>>(out_reg, W_cls, b_cls, out_cls);
}